// Round 1
// baseline (363.767 us; speedup 1.0000x reference)
//
#include <hip/hip_runtime.h>
#include <hip/hip_bf16.h>

// Problem constants (from reference)
#define Hd   768
#define Bsz  4
#define Ent  42
#define Mm   16
#define NEGV (-1e9f)

#define BM 64
#define BN 64
#define BK 32
#define PAD 4   // keep rows 16B-aligned: (BK+PAD)*4B = 144B = 9*16B

// ---------------------------------------------------------------------------
// Kernel A: C[r,o] = relu( sum_h A[r,h] * W[o,h] )   (A:[R,Hd], W:[Hd,Hd])
// ---------------------------------------------------------------------------
__global__ __launch_bounds__(256)
void gemm_relu_nt(const float* __restrict__ A,
                  const float* __restrict__ W,
                  float* __restrict__ C)
{
    __shared__ float As[BM][BK + PAD];
    __shared__ float Ws[BN][BK + PAD];

    const int tid = threadIdx.x;
    const int m0  = blockIdx.y * BM;
    const int n0  = blockIdx.x * BN;
    const int ty  = tid >> 4;     // 0..15
    const int tx  = tid & 15;     // 0..15

    // loader mapping: 64 rows x 8 float4 = 512 float4 per tile; 2 per thread
    const int lr = tid >> 2;      // 0..63
    const int lc = tid & 3;       // 0..3 (and lc+4)

    float acc[4][4] = {};

    for (int k0 = 0; k0 < Hd; k0 += BK) {
        const float4* Ag = reinterpret_cast<const float4*>(A + (size_t)(m0 + lr) * Hd + k0);
        const float4* Wg = reinterpret_cast<const float4*>(W + (size_t)(n0 + lr) * Hd + k0);
        float4 a0 = Ag[lc];
        float4 a1 = Ag[lc + 4];
        float4 w0 = Wg[lc];
        float4 w1 = Wg[lc + 4];

        __syncthreads();   // previous-iter LDS reads done before overwrite
        *reinterpret_cast<float4*>(&As[lr][lc * 4])      = a0;
        *reinterpret_cast<float4*>(&As[lr][lc * 4 + 16]) = a1;
        *reinterpret_cast<float4*>(&Ws[lr][lc * 4])      = w0;
        *reinterpret_cast<float4*>(&Ws[lr][lc * 4 + 16]) = w1;
        __syncthreads();

        #pragma unroll
        for (int k4 = 0; k4 < BK / 4; ++k4) {
            float4 av[4], wv[4];
            #pragma unroll
            for (int jm = 0; jm < 4; ++jm)
                av[jm] = *reinterpret_cast<const float4*>(&As[ty * 4 + jm][k4 * 4]);
            #pragma unroll
            for (int jn = 0; jn < 4; ++jn)
                wv[jn] = *reinterpret_cast<const float4*>(&Ws[tx * 4 + jn][k4 * 4]);
            #pragma unroll
            for (int jm = 0; jm < 4; ++jm)
                #pragma unroll
                for (int jn = 0; jn < 4; ++jn) {
                    acc[jm][jn] += av[jm].x * wv[jn].x;
                    acc[jm][jn] += av[jm].y * wv[jn].y;
                    acc[jm][jn] += av[jm].z * wv[jn].z;
                    acc[jm][jn] += av[jm].w * wv[jn].w;
                }
        }
    }

    #pragma unroll
    for (int jm = 0; jm < 4; ++jm) {
        float4 o;
        o.x = fmaxf(acc[jm][0], 0.f);
        o.y = fmaxf(acc[jm][1], 0.f);
        o.z = fmaxf(acc[jm][2], 0.f);
        o.w = fmaxf(acc[jm][3], 0.f);
        *reinterpret_cast<float4*>(&C[(size_t)(m0 + ty * 4 + jm) * Hd + n0 + tx * 4]) = o;
    }
}

// ---------------------------------------------------------------------------
// Kernel B: per-row dots  ch[r]=f_head[r]. w_c ; qt[r]=f_tail[r] . w_q ;
//           cqt[r]=f_tail[r] . w_cq
// ---------------------------------------------------------------------------
__global__ __launch_bounds__(256)
void row_dots(const float* __restrict__ f_head, const float* __restrict__ f_tail,
              const float* __restrict__ w_c, const float* __restrict__ w_q,
              const float* __restrict__ w_cq,
              float* __restrict__ ch, float* __restrict__ qt, float* __restrict__ cqt)
{
    const int r = blockIdx.x;
    const int tid = threadIdx.x;
    const float* fh = f_head + (size_t)r * Hd;
    const float* ft = f_tail + (size_t)r * Hd;

    float pc = 0.f, pq = 0.f, pcq = 0.f;
    for (int c = tid; c < Hd; c += 256) {
        float vh = fh[c], vt = ft[c];
        pc  += vh * w_c[c];
        pq  += vt * w_q[c];
        pcq += vt * w_cq[c];
    }
    __shared__ float red[3][256];
    red[0][tid] = pc; red[1][tid] = pq; red[2][tid] = pcq;
    __syncthreads();
    for (int s = 128; s >= 1; s >>= 1) {
        if (tid < s) {
            red[0][tid] += red[0][tid + s];
            red[1][tid] += red[1][tid + s];
            red[2][tid] += red[2][tid + s];
        }
        __syncthreads();
    }
    if (tid == 0) { ch[r] = red[0][0]; qt[r] = red[1][0]; cqt[r] = red[2][0]; }
}

// ---------------------------------------------------------------------------
// Kernel C: per-pair 16x16 score, dual softmax, weighted pooling, concat out
// ---------------------------------------------------------------------------
__global__ __launch_bounds__(256)
void pair_attn(const float* __restrict__ f_head, const float* __restrict__ f_tail,
               const float* __restrict__ ch, const float* __restrict__ qt,
               const float* __restrict__ cqt,
               const float* __restrict__ entity_embed,
               const int* __restrict__ mention_num,
               const int* __restrict__ b_ind, const int* __restrict__ h_ind,
               const int* __restrict__ t_ind,
               float* __restrict__ out, int N)
{
    const int n   = blockIdx.x;
    const int tid = threadIdx.x;
    const int b = b_ind[n], h = h_ind[n], t = t_ind[n];
    const int eh = b * Ent + h, et = b * Ent + t;
    const int rh = eh * Mm, rt = et * Mm;
    const int hn = mention_num[eh], tn = mention_num[et];

    __shared__ float sm[Mm][Mm];
    __shared__ float hw[Mm], tw[Mm];

    {
        const int i = tid >> 4, j = tid & 15;
        float v = ch[rh + i] + qt[rt + j] + cqt[rt + i] * f_head[(size_t)(rh + i) * Hd + j];
        if (i >= hn || j >= tn) v = NEGV;
        sm[i][j] = v;
    }
    __syncthreads();

    if (tid < Mm) {                 // row max (over j) -> hw
        float m = sm[tid][0];
        #pragma unroll
        for (int jj = 1; jj < Mm; ++jj) m = fmaxf(m, sm[tid][jj]);
        hw[tid] = m;
    } else if (tid < 2 * Mm) {      // col max (over i) -> tw
        const int c = tid - Mm;
        float m = sm[0][c];
        #pragma unroll
        for (int ii = 1; ii < Mm; ++ii) m = fmaxf(m, sm[ii][c]);
        tw[c] = m;
    }
    __syncthreads();

    if (tid == 0) {
        float mx = hw[0];
        #pragma unroll
        for (int ii = 1; ii < Mm; ++ii) mx = fmaxf(mx, hw[ii]);
        float e[Mm]; float s = 0.f;
        #pragma unroll
        for (int ii = 0; ii < Mm; ++ii) { e[ii] = expf(hw[ii] - mx); s += e[ii]; }
        const float inv = 1.f / s;
        #pragma unroll
        for (int ii = 0; ii < Mm; ++ii) hw[ii] = e[ii] * inv;
    } else if (tid == 64) {
        float mx = tw[0];
        #pragma unroll
        for (int ii = 1; ii < Mm; ++ii) mx = fmaxf(mx, tw[ii]);
        float e[Mm]; float s = 0.f;
        #pragma unroll
        for (int ii = 0; ii < Mm; ++ii) { e[ii] = expf(tw[ii] - mx); s += e[ii]; }
        const float inv = 1.f / s;
        #pragma unroll
        for (int ii = 0; ii < Mm; ++ii) tw[ii] = e[ii] * inv;
    }
    __syncthreads();

    // outputs: head_embed[n] = [entity_embed[eh], sum_i hw[i]*f_head[rh+i]]
    //          tail_embed[n] = [entity_embed[et], sum_j tw[j]*f_tail[rt+j]]
    const int oh = n * (2 * Hd);
    const int ot = (N + n) * (2 * Hd);
    for (int c = tid; c < Hd; c += 256) {
        out[oh + c] = entity_embed[(size_t)eh * Hd + c];
        out[ot + c] = entity_embed[(size_t)et * Hd + c];
        float a0 = 0.f, a1 = 0.f;
        #pragma unroll
        for (int ii = 0; ii < Mm; ++ii) {
            a0 += hw[ii] * f_head[(size_t)(rh + ii) * Hd + c];
            a1 += tw[ii] * f_tail[(size_t)(rt + ii) * Hd + c];
        }
        out[oh + Hd + c] = a0;
        out[ot + Hd + c] = a1;
    }
}

// ---------------------------------------------------------------------------
extern "C" void kernel_launch(void* const* d_in, const int* in_sizes, int n_in,
                              void* d_out, int out_size, void* d_ws, size_t ws_size,
                              hipStream_t stream)
{
    const float* entity_embed  = (const float*)d_in[0];
    const float* mention_embed = (const float*)d_in[1];
    // d_in[2] sent_embed  : unused by reference
    // d_in[3] entity_info : unused by reference
    const int*   mention_num   = (const int*)d_in[4];
    const int*   b_ind         = (const int*)d_in[5];
    const int*   h_ind         = (const int*)d_in[6];
    const int*   t_ind         = (const int*)d_in[7];
    const float* W_head        = (const float*)d_in[8];
    const float* W_tail        = (const float*)d_in[9];
    const float* w_c           = (const float*)d_in[10];
    const float* w_q           = (const float*)d_in[11];
    const float* w_cq          = (const float*)d_in[12];
    float* out = (float*)d_out;

    const int N = in_sizes[5];            // 4096
    const int R = Bsz * Ent * Mm;         // 2688

    float* f_head = (float*)d_ws;
    float* f_tail = f_head + (size_t)R * Hd;
    float* ch     = f_tail + (size_t)R * Hd;
    float* qt     = ch + R;
    float* cqt    = qt + R;

    dim3 gg(Hd / BN, R / BM);             // (12, 42)
    gemm_relu_nt<<<gg, 256, 0, stream>>>(mention_embed, W_head, f_head);
    gemm_relu_nt<<<gg, 256, 0, stream>>>(mention_embed, W_tail, f_tail);
    row_dots<<<R, 256, 0, stream>>>(f_head, f_tail, w_c, w_q, w_cq, ch, qt, cqt);
    pair_attn<<<N, 256, 0, stream>>>(f_head, f_tail, ch, qt, cqt,
                                     entity_embed, mention_num,
                                     b_ind, h_ind, t_ind, out, N);
}

// Round 2
// 62.473 us; speedup vs baseline: 5.8228x; 5.8228x over previous
//
#include <hip/hip_runtime.h>
#include <hip/hip_bf16.h>

// Problem constants (from reference)
#define Hd   768
#define Bsz  4
#define Ent  42
#define Mm   16
#define NEGV (-1e9f)

#define GM 2688          // B*E*M rows
#define GN 1536          // concat(head, tail) outputs
#define GK 768

typedef short bf16x8 __attribute__((ext_vector_type(8)));
typedef float f32x4  __attribute__((ext_vector_type(4)));
typedef unsigned short u16x8 __attribute__((ext_vector_type(8)));

static __device__ __forceinline__ unsigned short f2bf(float x) {
    unsigned int u = __float_as_uint(x);
    u += 0x7fffu + ((u >> 16) & 1u);          // RNE
    return (unsigned short)(u >> 16);
}
static __device__ __forceinline__ float bf2f(unsigned short v) {
    return __uint_as_float(((unsigned int)v) << 16);
}

// ---------------------------------------------------------------------------
// Kernel 0: fp32 -> bf16 conversion.  dst rows: [0,2688)=mention_embed,
// [2688,3456)=W_head, [3456,4224)=W_tail.  8 elems per thread.
// ---------------------------------------------------------------------------
__global__ __launch_bounds__(256)
void to_bf16(const float* __restrict__ me, const float* __restrict__ wh,
             const float* __restrict__ wt, unsigned short* __restrict__ dst)
{
    const int t = blockIdx.x * 256 + threadIdx.x;     // 405504 total
    const size_t e = (size_t)t * 8;
    const size_t row = e / Hd;                         // 8 | 768 so no straddle
    const float* src;
    size_t off;
    if (row < 2688)      { src = me; off = e; }
    else if (row < 3456) { src = wh; off = e - (size_t)2688 * Hd; }
    else                 { src = wt; off = e - (size_t)3456 * Hd; }
    float4 v0 = *reinterpret_cast<const float4*>(src + off);
    float4 v1 = *reinterpret_cast<const float4*>(src + off + 4);
    u16x8 o;
    o[0] = f2bf(v0.x); o[1] = f2bf(v0.y); o[2] = f2bf(v0.z); o[3] = f2bf(v0.w);
    o[4] = f2bf(v1.x); o[5] = f2bf(v1.y); o[6] = f2bf(v1.z); o[7] = f2bf(v1.w);
    *reinterpret_cast<u16x8*>(dst + e) = o;
}

// ---------------------------------------------------------------------------
// Kernel 1: bf16 MFMA GEMM + ReLU.  C[r,o] = relu(sum_k A[r,k]*W[o,k]).
// 64x64 tile, BK=32, 4 waves (2x2), each wave 32x32 via 2x2 16x16x32 frags.
// global_load_lds width=16, linear LDS (guide §5 step-3 structure).
// ---------------------------------------------------------------------------
__global__ __launch_bounds__(256)
void gemm_mfma(const unsigned short* __restrict__ Ab,
               const unsigned short* __restrict__ Wb,
               unsigned short* __restrict__ f_head,
               unsigned short* __restrict__ f_tail)
{
    __shared__ unsigned short As[64 * 32];
    __shared__ unsigned short Bs[64 * 32];

    const int tid  = threadIdx.x;
    const int wave = tid >> 6;
    const int lane = tid & 63;
    const int n0 = blockIdx.x * 64;
    const int m0 = blockIdx.y * 64;
    const int wr = wave >> 1;            // 0..1
    const int wc = wave & 1;             // 0..1

    // staging: wave stages 16 rows (1KB) of each tile; lane l -> +l*16B linear
    const int srow = wave * 16 + (lane >> 2);
    const int scol = (lane & 3) * 8;                    // elements
    const unsigned short* Aga = Ab + (size_t)(m0 + srow) * GK + scol;
    const unsigned short* Bga = Wb + (size_t)(n0 + srow) * GK + scol;
    unsigned short* AsDst = As + wave * 512;
    unsigned short* BsDst = Bs + wave * 512;

    const int frow = lane & 15;
    const int koff = (lane >> 4) * 8;

    f32x4 acc[2][2];
    {
        f32x4 z = {0.f, 0.f, 0.f, 0.f};
        acc[0][0] = z; acc[0][1] = z; acc[1][0] = z; acc[1][1] = z;
    }

    const unsigned short* ap = As + (wr * 32 + frow) * 32 + koff;
    const unsigned short* bp = Bs + (wc * 32 + frow) * 32 + koff;

    for (int k0 = 0; k0 < GK; k0 += 32) {
        __syncthreads();    // prev-iter LDS reads done before overwrite
        __builtin_amdgcn_global_load_lds(
            (const __attribute__((address_space(1))) void*)(Aga + k0),
            (__attribute__((address_space(3))) void*)AsDst, 16, 0, 0);
        __builtin_amdgcn_global_load_lds(
            (const __attribute__((address_space(1))) void*)(Bga + k0),
            (__attribute__((address_space(3))) void*)BsDst, 16, 0, 0);
        __syncthreads();    // compiler drains vmcnt before barrier

        bf16x8 a0 = *reinterpret_cast<const bf16x8*>(ap);
        bf16x8 a1 = *reinterpret_cast<const bf16x8*>(ap + 16 * 32);
        bf16x8 b0 = *reinterpret_cast<const bf16x8*>(bp);
        bf16x8 b1 = *reinterpret_cast<const bf16x8*>(bp + 16 * 32);
        acc[0][0] = __builtin_amdgcn_mfma_f32_16x16x32_bf16(a0, b0, acc[0][0], 0, 0, 0);
        acc[0][1] = __builtin_amdgcn_mfma_f32_16x16x32_bf16(a0, b1, acc[0][1], 0, 0, 0);
        acc[1][0] = __builtin_amdgcn_mfma_f32_16x16x32_bf16(a1, b0, acc[1][0], 0, 0, 0);
        acc[1][1] = __builtin_amdgcn_mfma_f32_16x16x32_bf16(a1, b1, acc[1][1], 0, 0, 0);
    }

    // C/D layout (m89-verified): col = lane&15, row = (lane>>4)*4 + reg
    const bool isHead = (n0 < Hd);
    unsigned short* outp = isHead ? f_head : f_tail;
    const int nbase = (isHead ? n0 : (n0 - Hd)) + wc * 32 + frow;
    const int rbase = m0 + wr * 32 + (lane >> 4) * 4;
    #pragma unroll
    for (int mi = 0; mi < 2; ++mi)
        #pragma unroll
        for (int ni = 0; ni < 2; ++ni)
            #pragma unroll
            for (int j = 0; j < 4; ++j) {
                float v = fmaxf(acc[mi][ni][j], 0.f);
                outp[(size_t)(rbase + mi * 16 + j) * Hd + nbase + ni * 16] = f2bf(v);
            }
}

// ---------------------------------------------------------------------------
// Kernel 2: per-row dots. One wave per row, shuffle reduce.
// ---------------------------------------------------------------------------
__global__ __launch_bounds__(256)
void row_dots(const unsigned short* __restrict__ f_head,
              const unsigned short* __restrict__ f_tail,
              const float* __restrict__ w_c, const float* __restrict__ w_q,
              const float* __restrict__ w_cq,
              float* __restrict__ ch, float* __restrict__ qt, float* __restrict__ cqt)
{
    const int wave = threadIdx.x >> 6;
    const int lane = threadIdx.x & 63;
    const int r = blockIdx.x * 4 + wave;
    const unsigned short* fh = f_head + (size_t)r * Hd;
    const unsigned short* ft = f_tail + (size_t)r * Hd;
    float pc = 0.f, pq = 0.f, pcq = 0.f;
    #pragma unroll
    for (int j = 0; j < Hd / 64; ++j) {
        const int c = j * 64 + lane;
        float vh = bf2f(fh[c]), vt = bf2f(ft[c]);
        pc += vh * w_c[c]; pq += vt * w_q[c]; pcq += vt * w_cq[c];
    }
    #pragma unroll
    for (int s = 32; s >= 1; s >>= 1) {
        pc  += __shfl_down(pc, s);
        pq  += __shfl_down(pq, s);
        pcq += __shfl_down(pcq, s);
    }
    if (lane == 0) { ch[r] = pc; qt[r] = pq; cqt[r] = pcq; }
}

// ---------------------------------------------------------------------------
// Kernel 3: per-pair 16x16 score, dual softmax, weighted pooling, concat out
// ---------------------------------------------------------------------------
__global__ __launch_bounds__(256)
void pair_attn(const unsigned short* __restrict__ f_head,
               const unsigned short* __restrict__ f_tail,
               const float* __restrict__ ch, const float* __restrict__ qt,
               const float* __restrict__ cqt,
               const float* __restrict__ entity_embed,
               const int* __restrict__ mention_num,
               const int* __restrict__ b_ind, const int* __restrict__ h_ind,
               const int* __restrict__ t_ind,
               float* __restrict__ out, int N)
{
    const int n   = blockIdx.x;
    const int tid = threadIdx.x;
    const int b = b_ind[n], h = h_ind[n], t = t_ind[n];
    const int eh = b * Ent + h, et = b * Ent + t;
    const int rh = eh * Mm, rt = et * Mm;
    const int hn = mention_num[eh], tn = mention_num[et];

    __shared__ float sm[Mm][Mm];
    __shared__ float hw[Mm], tw[Mm];

    {
        const int i = tid >> 4, j = tid & 15;
        float v = ch[rh + i] + qt[rt + j]
                + cqt[rt + i] * bf2f(f_head[(size_t)(rh + i) * Hd + j]);
        if (i >= hn || j >= tn) v = NEGV;
        sm[i][j] = v;
    }
    __syncthreads();

    if (tid < Mm) {                 // row max (over j) -> hw
        float m = sm[tid][0];
        #pragma unroll
        for (int jj = 1; jj < Mm; ++jj) m = fmaxf(m, sm[tid][jj]);
        hw[tid] = m;
    } else if (tid < 2 * Mm) {      // col max (over i) -> tw
        const int c = tid - Mm;
        float m = sm[0][c];
        #pragma unroll
        for (int ii = 1; ii < Mm; ++ii) m = fmaxf(m, sm[ii][c]);
        tw[c] = m;
    }
    __syncthreads();

    if (tid == 0) {
        float mx = hw[0];
        #pragma unroll
        for (int ii = 1; ii < Mm; ++ii) mx = fmaxf(mx, hw[ii]);
        float e[Mm]; float s = 0.f;
        #pragma unroll
        for (int ii = 0; ii < Mm; ++ii) { e[ii] = expf(hw[ii] - mx); s += e[ii]; }
        const float inv = 1.f / s;
        #pragma unroll
        for (int ii = 0; ii < Mm; ++ii) hw[ii] = e[ii] * inv;
    } else if (tid == 64) {
        float mx = tw[0];
        #pragma unroll
        for (int ii = 1; ii < Mm; ++ii) mx = fmaxf(mx, tw[ii]);
        float e[Mm]; float s = 0.f;
        #pragma unroll
        for (int ii = 0; ii < Mm; ++ii) { e[ii] = expf(tw[ii] - mx); s += e[ii]; }
        const float inv = 1.f / s;
        #pragma unroll
        for (int ii = 0; ii < Mm; ++ii) tw[ii] = e[ii] * inv;
    }
    __syncthreads();

    const int oh = n * (2 * Hd);
    const int ot = (N + n) * (2 * Hd);
    const unsigned short* fhp = f_head + (size_t)rh * Hd;
    const unsigned short* ftp = f_tail + (size_t)rt * Hd;
    for (int c = tid; c < Hd; c += 256) {
        out[oh + c] = entity_embed[(size_t)eh * Hd + c];
        out[ot + c] = entity_embed[(size_t)et * Hd + c];
        float a0 = 0.f, a1 = 0.f;
        #pragma unroll
        for (int ii = 0; ii < Mm; ++ii) {
            a0 += hw[ii] * bf2f(fhp[(size_t)ii * Hd + c]);
            a1 += tw[ii] * bf2f(ftp[(size_t)ii * Hd + c]);
        }
        out[oh + Hd + c] = a0;
        out[ot + Hd + c] = a1;
    }
}

// ---------------------------------------------------------------------------
extern "C" void kernel_launch(void* const* d_in, const int* in_sizes, int n_in,
                              void* d_out, int out_size, void* d_ws, size_t ws_size,
                              hipStream_t stream)
{
    const float* entity_embed  = (const float*)d_in[0];
    const float* mention_embed = (const float*)d_in[1];
    // d_in[2] sent_embed, d_in[3] entity_info: unused by reference
    const int*   mention_num   = (const int*)d_in[4];
    const int*   b_ind         = (const int*)d_in[5];
    const int*   h_ind         = (const int*)d_in[6];
    const int*   t_ind         = (const int*)d_in[7];
    const float* W_head        = (const float*)d_in[8];
    const float* W_tail        = (const float*)d_in[9];
    const float* w_c           = (const float*)d_in[10];
    const float* w_q           = (const float*)d_in[11];
    const float* w_cq          = (const float*)d_in[12];
    float* out = (float*)d_out;

    const int N = in_sizes[5];            // 4096

    // workspace layout (bf16 activations): total ~14.1 MiB
    unsigned short* Ab     = (unsigned short*)d_ws;          // [2688*768]
    unsigned short* Wb     = Ab + (size_t)GM * GK;           // [1536*768] (head||tail)
    unsigned short* f_head = Wb + (size_t)GN * GK;           // [2688*768]
    unsigned short* f_tail = f_head + (size_t)GM * Hd;       // [2688*768]
    float* ch  = (float*)(f_tail + (size_t)GM * Hd);
    float* qt  = ch + GM;
    float* cqt = qt + GM;

    // 0) convert inputs to bf16 (Ab and Wb are contiguous -> one kernel)
    to_bf16<<<(GM + GN) * GK / (8 * 256), 256, 0, stream>>>(
        mention_embed, W_head, W_tail, Ab);

    // 1) fused projection GEMM + ReLU -> bf16 f_head / f_tail
    dim3 gg(GN / 64, GM / 64);            // (24, 42)
    gemm_mfma<<<gg, 256, 0, stream>>>(Ab, Wb, f_head, f_tail);

    // 2) per-row dots
    row_dots<<<GM / 4, 256, 0, stream>>>(f_head, f_tail, w_c, w_q, w_cq, ch, qt, cqt);

    // 3) per-pair attention + output
    pair_attn<<<N, 256, 0, stream>>>(f_head, f_tail, ch, qt, cqt,
                                     entity_embed, mention_num,
                                     b_ind, h_ind, t_ind, out, N);
}